// Round 5
// baseline (119.056 us; speedup 1.0000x reference)
//
#include <hip/hip_runtime.h>
#include <hip/hip_fp16.h>

typedef __attribute__((ext_vector_type(8))) short short8;
typedef __attribute__((ext_vector_type(8))) __bf16 bf16x8;
typedef __attribute__((ext_vector_type(4))) float f32x4;
typedef __attribute__((ext_vector_type(16))) float f32x16;

#define DEV __device__ __forceinline__

DEV unsigned short f2bf(float f) {
    unsigned int u = __float_as_uint(f);
    return (unsigned short)((u + 0x7FFFu + ((u >> 16) & 1u)) >> 16);
}
DEV float bf2f(unsigned short s) { return __uint_as_float(((unsigned int)s) << 16); }
DEV bf16x8 asbf(short8 v) { return __builtin_bit_cast(bf16x8, v); }

// ---------------- prep kernel (feat cast + weight pack fused) ----------------
__global__ __launch_bounds__(256) void k_prep(const float* __restrict__ feat,
                                              const float* __restrict__ qw, const float* __restrict__ qb,
                                              const float* __restrict__ kvw, const float* __restrict__ kvb,
                                              const float* __restrict__ pew, const float* __restrict__ peb,
                                              const float* __restrict__ pret, const float* __restrict__ projw,
                                              unsigned short* __restrict__ featb,
                                              unsigned short* __restrict__ wqkv, float* __restrict__ bqkv,
                                              unsigned short* __restrict__ projwb, unsigned short* __restrict__ peAll) {
    const float scale = 0.17677669529663687f; // 1/sqrt(32)
    int i0 = blockIdx.x * 256 + threadIdx.x;
    if (i0 < 262144) {                        // feat f32 -> bf16, 8/thread
        const float4* f4 = (const float4*)feat + (size_t)i0 * 2;
        float4 a = f4[0], c = f4[1];
        short8 o;
        o[0] = (short)f2bf(a.x); o[1] = (short)f2bf(a.y);
        o[2] = (short)f2bf(a.z); o[3] = (short)f2bf(a.w);
        o[4] = (short)f2bf(c.x); o[5] = (short)f2bf(c.y);
        o[6] = (short)f2bf(c.z); o[7] = (short)f2bf(c.w);
        ((short8*)featb)[i0] = o;
        return;
    }
    int i = i0 - 262144;
    if (i < 786432) {                         // wqkv [1536][512]
        int o = i >> 9, k = i & 511;
        float v = (o < 512) ? qw[(o << 9) + k] * scale : kvw[((o - 512) << 9) + k];
        wqkv[i] = f2bf(v);
    } else if (i < 786432 + 262144) {
        int j = i - 786432;
        projwb[j] = f2bf(projw[j]);
    } else if (i < 786432 + 262144 + 1536) {
        int o = i - (786432 + 262144);
        bqkv[o] = (o < 512) ? qb[o] * scale : kvb[o - 512];
    } else if (i < 786432 + 262144 + 1536 + 65536) { // peAll[t][16] f16
        int j = i - (786432 + 262144 + 1536);
        int t = j >> 4, h = j & 15;
        float s = peb[h];
#pragma unroll
        for (int u = 0; u < 5; u++) s += pret[t * 5 + u] * pew[h * 5 + u];
        peAll[j] = __builtin_bit_cast(unsigned short, __float2half(s));
    }
}

// ---------------- QKV GEMM ----------------
__global__ __launch_bounds__(256) void k_qkv(const unsigned short* __restrict__ A,
                                             const unsigned short* __restrict__ Bw,
                                             const float* __restrict__ bias,
                                             unsigned short* __restrict__ Qh,
                                             unsigned short* __restrict__ Kh,
                                             unsigned short* __restrict__ Vt) {
    __shared__ __align__(16) unsigned short As[128][72];
    __shared__ __align__(16) unsigned short Bs[64][72];
    int tid = threadIdx.x, lane = tid & 63, wid = tid >> 6;
    int m0 = blockIdx.y * 128, n0 = blockIdx.x * 64;
    int wm = wid >> 1, wn = wid & 1;
    f32x4 acc[4][2] = {};

    for (int k0 = 0; k0 < 512; k0 += 64) {
        {
            int row = tid >> 1, cs = (tid & 1) * 32;
            const short8* src = (const short8*)(A + (size_t)(m0 + row) * 512 + k0 + cs);
            short8* dst = (short8*)(&As[row][cs]);
            dst[0] = src[0]; dst[1] = src[1]; dst[2] = src[2]; dst[3] = src[3];
        }
        {
            int row = tid >> 2, cs = (tid & 3) * 16;
            const short8* src = (const short8*)(Bw + (size_t)(n0 + row) * 512 + k0 + cs);
            short8* dst = (short8*)(&Bs[row][cs]);
            dst[0] = src[0]; dst[1] = src[1];
        }
        __syncthreads();
#pragma unroll
        for (int kk = 0; kk < 64; kk += 32) {
            short8 a[4], b[2];
#pragma unroll
            for (int m = 0; m < 4; m++)
                a[m] = *(const short8*)(&As[wm * 64 + m * 16 + (lane & 15)][kk + ((lane >> 4) << 3)]);
#pragma unroll
            for (int n = 0; n < 2; n++)
                b[n] = *(const short8*)(&Bs[wn * 32 + n * 16 + (lane & 15)][kk + ((lane >> 4) << 3)]);
#pragma unroll
            for (int m = 0; m < 4; m++) {
#pragma unroll
                for (int n = 0; n < 2; n++)
                    acc[m][n] = __builtin_amdgcn_mfma_f32_16x16x32_bf16(asbf(a[m]), asbf(b[n]), acc[m][n], 0, 0, 0);
            }
        }
        __syncthreads();
    }
#pragma unroll
    for (int m = 0; m < 4; m++) {
#pragma unroll
        for (int n = 0; n < 2; n++) {
            int col = n0 + wn * 32 + n * 16 + (lane & 15);
            float bv = bias[col];
#pragma unroll
            for (int r = 0; r < 4; r++) {
                int row = m0 + wm * 64 + m * 16 + ((lane >> 4) << 2) + r;
                float v = acc[m][n][r] + bv;
                unsigned short bb = f2bf(v);
                int batch = row >> 10, nn = row & 1023;
                if (col < 512) {
                    int h = col >> 5, d = col & 31;
                    Qh[((((batch << 4) + h) << 10) + nn) * 32 + d] = bb;
                } else {
                    int oo = col - 512, h = oo >> 6, rem = oo & 63;
                    if (rem < 32)
                        Kh[((((batch << 4) + h) << 10) + nn) * 32 + rem] = bb;
                    else
                        Vt[(((batch << 4) + h) * 32 + (rem - 32)) * 1024 + nn] = bb;
                }
            }
        }
    }
}

// ---------------- fused attention: 8 heads/block, V via wave-private LDS ----------------
// grid 512: b=bid&3, qt=(bid>>2)&31, kc=(bid>>7)&1, hg=bid>>8
// 512 threads = 8 waves; wave w -> head hg*8+w; q-tile 32; k-chunk 512 in 8 tiles of 64
__global__ __launch_bounds__(512, 4) void k_attn(const unsigned short* __restrict__ Qh,
                                                 const unsigned short* __restrict__ Kh,
                                                 const unsigned short* __restrict__ Vt,
                                                 const int* __restrict__ pe_idx,
                                                 const unsigned short* __restrict__ peAll,
                                                 const float* __restrict__ blank_k,
                                                 float* __restrict__ partial,
                                                 float* __restrict__ ml,
                                                 float* __restrict__ lbuf) {
    __shared__ __align__(16) unsigned int posb[4][32][72];     // 36 KB pos slabs (2 heads/dword)
    __shared__ __align__(16) unsigned short Vs[8][32][72];     // 36 KB wave-private V tiles [d][k+pad]

    int tid = threadIdx.x, lane = tid & 63, w = tid >> 6;
    int q5 = lane & 31, hi = lane >> 5;
    int bid = blockIdx.x;
    int b = bid & 3, qt = (bid >> 2) & 31, kc = (bid >> 7) & 1, hg = bid >> 8;
    int q0 = qt * 32, k_base = kc * 512;
    int head = hg * 8 + w, bh = (b << 4) + head;
    int slab = w >> 1, halfsel = w & 1;

    // gather-phase map: thread -> (q row, 4 consecutive k)
    int gq = tid >> 4, gk = (tid & 15) * 4;
    const int* pebase = pe_idx + ((size_t)((b << 10) + q0 + gq)) * 1024 + k_base + gk;
    const unsigned short* peg = peAll + hg * 8;   // this head-group's 16B half-row

    // V staging map: load j -> row vd = j*8 + (lane>>3), col vk8 = (lane&7)*8
    int vd_off = lane >> 3, vk8 = (lane & 7) * 8;
    const unsigned short* vtb = Vt + (size_t)(bh * 32) * 1024 + k_base + vk8;

    short8 qf[2];
    float lb_, m_run, l_run;
    f32x16 accO = {};
    const f32x16 zero16 = {};

    {
#pragma unroll
        for (int sub = 0; sub < 2; sub++)
            qf[sub] = *(const short8*)(Qh + ((size_t)((bh << 10) + q0 + q5)) * 32 + sub * 16 + hi * 8);
        float dot = 0.f;
#pragma unroll
        for (int sub = 0; sub < 2; sub++) {
            const float* bk = blank_k + head * 32 + sub * 16 + hi * 8;
#pragma unroll
            for (int t = 0; t < 8; t++) dot += bf2f((unsigned short)qf[sub][t]) * bk[t];
        }
        dot += __shfl_xor(dot, 32, 64);
        lb_ = dot;
        m_run = (kc == 0) ? dot : -1e30f;
        l_run = (kc == 0) ? 1.0f : 0.0f;
    }

    // prologue: gather tile 0 (gg) + V tile 0 (vreg)
    unsigned gg[4][4];
    uint4 vreg[4];
    {
        int4 idx = *(const int4*)(pebase);
        int id[4] = {idx.x, idx.y, idx.z, idx.w};
#pragma unroll
        for (int j = 0; j < 4; j++) {
            uint4 a = *(const uint4*)(peg + ((size_t)id[j] << 4));
            gg[0][j] = a.x; gg[1][j] = a.y; gg[2][j] = a.z; gg[3][j] = a.w;
        }
#pragma unroll
        for (int j = 0; j < 4; j++)
            vreg[j] = *(const uint4*)(vtb + (size_t)(j * 8 + vd_off) * 1024);
    }

    for (int kt = 0; kt < 8; kt++) {
        __syncthreads();                       // posb (prev tile) fully consumed
#pragma unroll
        for (int p = 0; p < 4; p++) {          // pos slab writes, b128 bank-floor
            uint4 o = {gg[p][0], gg[p][1], gg[p][2], gg[p][3]};
            *(uint4*)&posb[p][gq][gk] = o;
        }
        __syncthreads();                       // posb[kt] ready

        // wave-private V tile write (no barrier needed)
#pragma unroll
        for (int j = 0; j < 4; j++)
            *(uint4*)&Vs[w][j * 8 + vd_off][vk8] = vreg[j];

        // prefetch kt+1 (issued at compute start: full compute phase hides latency
        // before the compiler's vmcnt(0) drain at next barrier)
        if (kt < 7) {
            int4 idx = *(const int4*)(pebase + (kt + 1) * 64);
            int id[4] = {idx.x, idx.y, idx.z, idx.w};
#pragma unroll
            for (int j = 0; j < 4; j++) {
                uint4 a = *(const uint4*)(peg + ((size_t)id[j] << 4));
                gg[0][j] = a.x; gg[1][j] = a.y; gg[2][j] = a.z; gg[3][j] = a.w;
            }
#pragma unroll
            for (int j = 0; j < 4; j++)
                vreg[j] = *(const uint4*)(vtb + (size_t)(j * 8 + vd_off) * 1024 + (kt + 1) * 64);
        }

        int kg0 = k_base + kt * 64;
        // S^T = K x Q^T (32k x 32q), rows k=(r&3)+8*(r>>2)+4*hi, col q=q5
        f32x16 st[2];
#pragma unroll
        for (int ks = 0; ks < 2; ks++) {
            const unsigned short* kp = Kh + ((size_t)((bh << 10) + kg0 + ks * 32 + q5)) * 32 + hi * 8;
            short8 kf0 = *(const short8*)(kp);
            short8 kf1 = *(const short8*)(kp + 16);
            st[ks] = __builtin_amdgcn_mfma_f32_32x32x16_bf16(asbf(kf0), asbf(qf[0]), zero16, 0, 0, 0);
            st[ks] = __builtin_amdgcn_mfma_f32_32x32x16_bf16(asbf(kf1), asbf(qf[1]), st[ks], 0, 0, 0);
        }
        // pos add (lazy b128 reads from slab) + tile max
        float mx = -1e30f;
#pragma unroll
        for (int ks = 0; ks < 2; ks++)
#pragma unroll
            for (int rr = 0; rr < 4; rr++) {
                uint4 v = *(const uint4*)&posb[slab][q5][ks * 32 + rr * 8 + hi * 4];
                unsigned pv[4] = {v.x, v.y, v.z, v.w};
#pragma unroll
                for (int c = 0; c < 4; c++) {
                    __half2 h2 = __builtin_bit_cast(__half2, pv[c]);
                    int r = rr * 4 + c;
                    st[ks][r] += halfsel ? __high2float(h2) : __low2float(h2);
                    mx = fmaxf(mx, st[ks][r]);
                }
            }
        mx = fmaxf(mx, __shfl_xor(mx, 32, 64));
        // defer-max (T13)
        if (!__all(mx <= m_run + 8.0f)) {
            float mn = fmaxf(m_run, mx);
            float fac = __expf(m_run - mn);
            m_run = mn;
            l_run *= fac;
#pragma unroll
            for (int r = 0; r < 16; r++) {
                int qrow = (r & 3) + 8 * (r >> 2) + 4 * hi;
                float facr = __shfl(fac, qrow, 64);
                accO[r] *= facr;
            }
        }
        float sum = 0.f;
#pragma unroll
        for (int ks = 0; ks < 2; ks++)
#pragma unroll
            for (int r = 0; r < 16; r++) {
                float p = __expf(st[ks][r] - m_run);
                st[ks][r] = p;
                sum += p;
            }
        sum += __shfl_xor(sum, 32, 64);
        l_run += sum;
        // P -> A-frag via v_cvt_pk_bf16_f32 + permlane32_swap (T12), then PV (V from LDS)
#pragma unroll
        for (int ks = 0; ks < 2; ks++) {
            unsigned pk_[8];
#pragma unroll
            for (int i = 0; i < 8; i++) {
                float plo = st[ks][2 * i], phi = st[ks][2 * i + 1];
                asm("v_cvt_pk_bf16_f32 %0, %1, %2" : "=v"(pk_[i]) : "v"(plo), "v"(phi));
            }
            asm("v_permlane32_swap_b32 %0, %1" : "+v"(pk_[0]), "+v"(pk_[2]));
            asm("v_permlane32_swap_b32 %0, %1" : "+v"(pk_[1]), "+v"(pk_[3]));
            asm("v_permlane32_swap_b32 %0, %1" : "+v"(pk_[4]), "+v"(pk_[6]));
            asm("v_permlane32_swap_b32 %0, %1" : "+v"(pk_[5]), "+v"(pk_[7]));
            uint4 u0 = {pk_[0], pk_[1], pk_[2], pk_[3]};
            uint4 u1 = {pk_[4], pk_[5], pk_[6], pk_[7]};
            short8 pa0 = __builtin_bit_cast(short8, u0);
            short8 pa1 = __builtin_bit_cast(short8, u1);
            short8 vf0 = *(const short8*)(&Vs[w][q5][ks * 32 + hi * 8]);
            short8 vf1 = *(const short8*)(&Vs[w][q5][ks * 32 + 16 + hi * 8]);
            accO = __builtin_amdgcn_mfma_f32_32x32x16_bf16(asbf(pa0), asbf(vf0), accO, 0, 0, 0);
            accO = __builtin_amdgcn_mfma_f32_32x32x16_bf16(asbf(pa1), asbf(vf1), accO, 0, 0, 0);
        }
    }

    // epilogue
    {
        size_t base = ((size_t)((b * 2 + kc) * 16 + head)) << 10;
#pragma unroll
        for (int r = 0; r < 16; r++) {
            int qrow = (r & 3) + 8 * (r >> 2) + 4 * hi;
            partial[(base + q0 + qrow) * 32 + q5] = accO[r];
        }
        if (hi == 0) {
            ml[(base + q0 + q5) * 2 + 0] = m_run;
            ml[(base + q0 + q5) * 2 + 1] = l_run;
            if (kc == 0)
                lbuf[(((size_t)((b << 4) + head)) << 10) + q0 + q5] = lb_;
        }
    }
}

// ---------------- combine partials + blank (x4 vectorized) ----------------
__global__ __launch_bounds__(256) void k_comb(const float* __restrict__ partial,
                                              const float* __restrict__ ml,
                                              const float* __restrict__ lbuf,
                                              const float* __restrict__ blank_v,
                                              unsigned short* __restrict__ attnO) {
    int t = blockIdx.x * 256 + threadIdx.x;     // 524288 threads
    int d4 = (t & 7) * 4;
    int row = t >> 3;                            // (b*16+h)*1024 + q
    int b = row >> 14, h = (row >> 10) & 15, q = row & 1023;
    size_t iA = ((size_t)((b * 2 + 0) * 16 + h) << 10) + q;
    size_t iB = ((size_t)((b * 2 + 1) * 16 + h) << 10) + q;
    float mA = ml[iA * 2], lA = ml[iA * 2 + 1];
    float mB = ml[iB * 2], lB = ml[iB * 2 + 1];
    float lb = lbuf[row];
    float M = fmaxf(mA, mB);
    float eA = __expf(mA - M), eB = __expf(mB - M);
    float L = lA * eA + lB * eB;
    float invL = 1.0f / L;
    float bw = __expf(lb - M) * invL;
    float4 pA = *(const float4*)&partial[iA * 32 + d4];
    float4 pB = *(const float4*)&partial[iB * 32 + d4];
    float4 bv = *(const float4*)&blank_v[h * 32 + d4];
    unsigned short o[4];
    o[0] = f2bf((pA.x * eA + pB.x * eB) * invL + bw * bv.x);
    o[1] = f2bf((pA.y * eA + pB.y * eB) * invL + bw * bv.y);
    o[2] = f2bf((pA.z * eA + pB.z * eB) * invL + bw * bv.z);
    o[3] = f2bf((pA.w * eA + pB.w * eB) * invL + bw * bv.w);
    *(uint2*)&attnO[((size_t)((b << 10) + q)) * 512 + h * 32 + d4] = *(uint2*)o;
}

// ---------------- final projection GEMM ----------------
__global__ __launch_bounds__(256) void k_proj(const unsigned short* __restrict__ A,
                                              const unsigned short* __restrict__ Bw,
                                              const float* __restrict__ bias,
                                              float* __restrict__ out) {
    __shared__ __align__(16) unsigned short As[128][72];
    __shared__ __align__(16) unsigned short Bs[64][72];
    int tid = threadIdx.x, lane = tid & 63, wid = tid >> 6;
    int m0 = blockIdx.y * 128, n0 = blockIdx.x * 64;
    int wm = wid >> 1, wn = wid & 1;
    f32x4 acc[4][2] = {};

    for (int k0 = 0; k0 < 512; k0 += 64) {
        {
            int row = tid >> 1, cs = (tid & 1) * 32;
            const short8* src = (const short8*)(A + (size_t)(m0 + row) * 512 + k0 + cs);
            short8* dst = (short8*)(&As[row][cs]);
            dst[0] = src[0]; dst[1] = src[1]; dst[2] = src[2]; dst[3] = src[3];
        }
        {
            int row = tid >> 2, cs = (tid & 3) * 16;
            const short8* src = (const short8*)(Bw + (size_t)(n0 + row) * 512 + k0 + cs);
            short8* dst = (short8*)(&Bs[row][cs]);
            dst[0] = src[0]; dst[1] = src[1];
        }
        __syncthreads();
#pragma unroll
        for (int kk = 0; kk < 64; kk += 32) {
            short8 a[4], b[2];
#pragma unroll
            for (int m = 0; m < 4; m++)
                a[m] = *(const short8*)(&As[wm * 64 + m * 16 + (lane & 15)][kk + ((lane >> 4) << 3)]);
#pragma unroll
            for (int n = 0; n < 2; n++)
                b[n] = *(const short8*)(&Bs[wn * 32 + n * 16 + (lane & 15)][kk + ((lane >> 4) << 3)]);
#pragma unroll
            for (int m = 0; m < 4; m++) {
#pragma unroll
                for (int n = 0; n < 2; n++)
                    acc[m][n] = __builtin_amdgcn_mfma_f32_16x16x32_bf16(asbf(a[m]), asbf(b[n]), acc[m][n], 0, 0, 0);
            }
        }
        __syncthreads();
    }
#pragma unroll
    for (int m = 0; m < 4; m++) {
#pragma unroll
        for (int n = 0; n < 2; n++) {
            int col = n0 + wn * 32 + n * 16 + (lane & 15);
            float bv = bias[col];
#pragma unroll
            for (int r = 0; r < 4; r++) {
                int row = m0 + wm * 64 + m * 16 + ((lane >> 4) << 2) + r;
                out[(size_t)row * 512 + col] = acc[m][n][r] + bv;
            }
        }
    }
}

extern "C" void kernel_launch(void* const* d_in, const int* in_sizes, int n_in,
                              void* d_out, int out_size, void* d_ws, size_t ws_size,
                              hipStream_t stream) {
    const float* feat    = (const float*)d_in[0];
    const int*   pe_idx  = (const int*)d_in[3];
    const float* pret    = (const float*)d_in[5];
    const float* qw      = (const float*)d_in[6];
    const float* qb      = (const float*)d_in[7];
    const float* kvw     = (const float*)d_in[8];
    const float* kvb     = (const float*)d_in[9];
    const float* pew     = (const float*)d_in[10];
    const float* peb     = (const float*)d_in[11];
    const float* blank_k = (const float*)d_in[12];
    const float* blank_v = (const float*)d_in[13];
    const float* projw   = (const float*)d_in[14];
    const float* projb   = (const float*)d_in[15];

    char* ws = (char*)d_ws;
    unsigned short* featb  = (unsigned short*)(ws);                  // 4 MB (reused as attnO)
    unsigned short* wqkv   = (unsigned short*)(ws + 4194304);        // 1.5 MB
    unsigned short* projwb = (unsigned short*)(ws + 5767168);        // 0.5 MB
    float*          bqkv   = (float*)(ws + 6291456);                 // 6 KB
    unsigned short* peAll  = (unsigned short*)(ws + 6297600);        // 128 KB
    unsigned short* Qh     = (unsigned short*)(ws + 6428672);        // 4 MB
    unsigned short* Kh     = (unsigned short*)(ws + 10622976);       // 4 MB
    unsigned short* Vt     = (unsigned short*)(ws + 14817280);       // 4 MB
    float*          partial= (float*)(ws + 19011584);                // 16 MB
    float*          mlb    = (float*)(ws + 35788800);                // 1 MB
    float*          lbuf   = (float*)(ws + 36837376);                // 256 KB
    unsigned short* attnO  = featb;                                  // alias (featb dead after k_qkv)

    k_prep<<<dim3(5382), dim3(256), 0, stream>>>(feat, qw, qb, kvw, kvb, pew, peb, pret, projw,
                                                 featb, wqkv, bqkv, projwb, peAll);
    k_qkv<<<dim3(24, 32), dim3(256), 0, stream>>>(featb, wqkv, bqkv, Qh, Kh, Vt);
    k_attn<<<dim3(512), dim3(512), 0, stream>>>(Qh, Kh, Vt, pe_idx, peAll, blank_k,
                                                partial, mlb, lbuf);
    k_comb<<<dim3(2048), dim3(256), 0, stream>>>(partial, mlb, lbuf, blank_v, attnO);
    k_proj<<<dim3(8, 32), dim3(256), 0, stream>>>(attnO, projwb, projb, (float*)d_out);
}

// Round 6
// 91.072 us; speedup vs baseline: 1.3073x; 1.3073x over previous
//
#include <hip/hip_runtime.h>
#include <hip/hip_fp16.h>

typedef __attribute__((ext_vector_type(8))) short short8;
typedef __attribute__((ext_vector_type(8))) __bf16 bf16x8;
typedef __attribute__((ext_vector_type(4))) float f32x4;
typedef __attribute__((ext_vector_type(16))) float f32x16;

#define DEV __device__ __forceinline__

DEV unsigned short f2bf(float f) {
    unsigned int u = __float_as_uint(f);
    return (unsigned short)((u + 0x7FFFu + ((u >> 16) & 1u)) >> 16);
}
DEV float bf2f(unsigned short s) { return __uint_as_float(((unsigned int)s) << 16); }
DEV bf16x8 asbf(short8 v) { return __builtin_bit_cast(bf16x8, v); }

// ---------------- prep kernel (feat cast + weight pack fused) ----------------
__global__ __launch_bounds__(256) void k_prep(const float* __restrict__ feat,
                                              const float* __restrict__ qw, const float* __restrict__ qb,
                                              const float* __restrict__ kvw, const float* __restrict__ kvb,
                                              const float* __restrict__ pew, const float* __restrict__ peb,
                                              const float* __restrict__ pret, const float* __restrict__ projw,
                                              unsigned short* __restrict__ featb,
                                              unsigned short* __restrict__ wqkv, float* __restrict__ bqkv,
                                              unsigned short* __restrict__ projwb, unsigned short* __restrict__ peAll) {
    const float scale = 0.17677669529663687f; // 1/sqrt(32)
    int i0 = blockIdx.x * 256 + threadIdx.x;
    if (i0 < 262144) {                        // feat f32 -> bf16, 8/thread
        const float4* f4 = (const float4*)feat + (size_t)i0 * 2;
        float4 a = f4[0], c = f4[1];
        short8 o;
        o[0] = (short)f2bf(a.x); o[1] = (short)f2bf(a.y);
        o[2] = (short)f2bf(a.z); o[3] = (short)f2bf(a.w);
        o[4] = (short)f2bf(c.x); o[5] = (short)f2bf(c.y);
        o[6] = (short)f2bf(c.z); o[7] = (short)f2bf(c.w);
        ((short8*)featb)[i0] = o;
        return;
    }
    int i = i0 - 262144;
    if (i < 786432) {                         // wqkv [1536][512]
        int o = i >> 9, k = i & 511;
        float v = (o < 512) ? qw[(o << 9) + k] * scale : kvw[((o - 512) << 9) + k];
        wqkv[i] = f2bf(v);
    } else if (i < 786432 + 262144) {
        int j = i - 786432;
        projwb[j] = f2bf(projw[j]);
    } else if (i < 786432 + 262144 + 1536) {
        int o = i - (786432 + 262144);
        bqkv[o] = (o < 512) ? qb[o] * scale : kvb[o - 512];
    } else if (i < 786432 + 262144 + 1536 + 65536) { // peAll[t][16] f16
        int j = i - (786432 + 262144 + 1536);
        int t = j >> 4, h = j & 15;
        float s = peb[h];
#pragma unroll
        for (int u = 0; u < 5; u++) s += pret[t * 5 + u] * pew[h * 5 + u];
        peAll[j] = __builtin_bit_cast(unsigned short, __float2half(s));
    }
}

// ---------------- QKV GEMM (epilogue scatters into MFMA-fragment order) ----------------
// Qf: [bh][qt(32)][sub(2)][lane(64)][8]   q = qt*32+q5, d = sub*16+hi*8+j, lane=hi*32+q5
// Kf: [bh][kt(16)][ks(2)][half(2)][lane][8]  n = kt*64+ks*32+q5, d = half*16+hi*8+j
// Vf: [bh][kt(16)][ks(2)][half(2)][lane][8]  d = q5, n = kt*64+ks*32+half*16+hi*8+j
__global__ __launch_bounds__(256) void k_qkv(const unsigned short* __restrict__ A,
                                             const unsigned short* __restrict__ Bw,
                                             const float* __restrict__ bias,
                                             unsigned short* __restrict__ Qf,
                                             unsigned short* __restrict__ Kf,
                                             unsigned short* __restrict__ Vf) {
    __shared__ __align__(16) unsigned short As[128][72];
    __shared__ __align__(16) unsigned short Bs[64][72];
    int tid = threadIdx.x, lane = tid & 63, wid = tid >> 6;
    int m0 = blockIdx.y * 128, n0 = blockIdx.x * 64;
    int wm = wid >> 1, wn = wid & 1;
    f32x4 acc[4][2] = {};

    for (int k0 = 0; k0 < 512; k0 += 64) {
        {
            int row = tid >> 1, cs = (tid & 1) * 32;
            const short8* src = (const short8*)(A + (size_t)(m0 + row) * 512 + k0 + cs);
            short8* dst = (short8*)(&As[row][cs]);
            dst[0] = src[0]; dst[1] = src[1]; dst[2] = src[2]; dst[3] = src[3];
        }
        {
            int row = tid >> 2, cs = (tid & 3) * 16;
            const short8* src = (const short8*)(Bw + (size_t)(n0 + row) * 512 + k0 + cs);
            short8* dst = (short8*)(&Bs[row][cs]);
            dst[0] = src[0]; dst[1] = src[1];
        }
        __syncthreads();
#pragma unroll
        for (int kk = 0; kk < 64; kk += 32) {
            short8 a[4], b[2];
#pragma unroll
            for (int m = 0; m < 4; m++)
                a[m] = *(const short8*)(&As[wm * 64 + m * 16 + (lane & 15)][kk + ((lane >> 4) << 3)]);
#pragma unroll
            for (int n = 0; n < 2; n++)
                b[n] = *(const short8*)(&Bs[wn * 32 + n * 16 + (lane & 15)][kk + ((lane >> 4) << 3)]);
#pragma unroll
            for (int m = 0; m < 4; m++) {
#pragma unroll
                for (int n = 0; n < 2; n++)
                    acc[m][n] = __builtin_amdgcn_mfma_f32_16x16x32_bf16(asbf(a[m]), asbf(b[n]), acc[m][n], 0, 0, 0);
            }
        }
        __syncthreads();
    }
#pragma unroll
    for (int m = 0; m < 4; m++) {
#pragma unroll
        for (int n = 0; n < 2; n++) {
            int col = n0 + wn * 32 + n * 16 + (lane & 15);
            float bv = bias[col];
#pragma unroll
            for (int r = 0; r < 4; r++) {
                int row = m0 + wm * 64 + m * 16 + ((lane >> 4) << 2) + r;
                float v = acc[m][n][r] + bv;
                unsigned short bb = f2bf(v);
                int batch = row >> 10, nn = row & 1023;
                if (col < 512) {            // Q
                    int h = col >> 5, d = col & 31;
                    int bh = (batch << 4) + h;
                    int qt = nn >> 5, q5 = nn & 31;
                    int sub = d >> 4, hi = (d >> 3) & 1, j = d & 7;
                    Qf[((((size_t)(bh * 32 + qt) * 2 + sub) * 64) + hi * 32 + q5) * 8 + j] = bb;
                } else {
                    int oo = col - 512, h = oo >> 6, rem = oo & 63;
                    int bh = (batch << 4) + h;
                    int kt = nn >> 6, ks = (nn >> 5) & 1;
                    if (rem < 32) {         // K: d = rem
                        int d = rem, half = d >> 4, hi = (d >> 3) & 1, j = d & 7, q5 = nn & 31;
                        Kf[((((size_t)((bh * 16 + kt) * 2 + ks) * 2 + half) * 64) + hi * 32 + q5) * 8 + j] = bb;
                    } else {                // V: d = rem-32, frag row = d, cols n
                        int d = rem - 32, nb = nn & 31;
                        int half = nb >> 4, hi = (nb >> 3) & 1, j = nb & 7;
                        Vf[((((size_t)((bh * 16 + kt) * 2 + ks) * 2 + half) * 64) + hi * 32 + d) * 8 + j] = bb;
                    }
                }
            }
        }
    }
}

// ---------------- fused attention: frag-ordered coalesced loads, 1 barrier/tile ----------------
// grid 512: b=bid&3, qt=(bid>>2)&31, kc=(bid>>7)&1, hg=bid>>8
// 512 threads = 8 waves; wave w -> head hg*8+w; q-tile 32; k-chunk 512 in 8 tiles of 64
__global__ __launch_bounds__(512, 4) void k_attn(const unsigned short* __restrict__ Qf,
                                                 const unsigned short* __restrict__ Kf,
                                                 const unsigned short* __restrict__ Vf,
                                                 const int* __restrict__ pe_idx,
                                                 const unsigned short* __restrict__ peAll,
                                                 const float* __restrict__ blank_k,
                                                 float* __restrict__ partial,
                                                 float* __restrict__ ml,
                                                 float* __restrict__ lbuf) {
    __shared__ __align__(16) unsigned int posb[2][4][32][72];  // 72 KB double-buffered pos slabs

    int tid = threadIdx.x, lane = tid & 63, w = tid >> 6;
    int q5 = lane & 31, hi = lane >> 5;
    int bid = blockIdx.x;
    int b = bid & 3, qt = (bid >> 2) & 31, kc = (bid >> 7) & 1, hg = bid >> 8;
    int q0 = qt * 32;
    int head = hg * 8 + w, bh = (b << 4) + head;
    int slab = w >> 1, halfsel = w & 1;

    // gather-phase map: thread -> (q row, 4 consecutive k)
    int gq = tid >> 4, gk = (tid & 15) * 4;
    const int* pebase = pe_idx + ((size_t)((b << 10) + q0 + gq)) * 1024 + kc * 512 + gk;
    const unsigned short* peg = peAll + hg * 8;   // this head-group's 16B half-row

    short8 qf[2];
    float lb_, m_run, l_run;
    f32x16 accO = {};
    const f32x16 zero16 = {};

    {
        const unsigned short* qb_ = Qf + ((size_t)(bh * 32 + qt) * 2) * 512 + lane * 8;
        qf[0] = *(const short8*)(qb_);
        qf[1] = *(const short8*)(qb_ + 512);
        float dot = 0.f;
#pragma unroll
        for (int sub = 0; sub < 2; sub++) {
            const float* bk = blank_k + head * 32 + sub * 16 + hi * 8;
#pragma unroll
            for (int t = 0; t < 8; t++) dot += bf2f((unsigned short)qf[sub][t]) * bk[t];
        }
        dot += __shfl_xor(dot, 32, 64);
        lb_ = dot;
        m_run = (kc == 0) ? dot : -1e30f;
        l_run = (kc == 0) ? 1.0f : 0.0f;
    }

    // prologue: gather tile 0 into regs, write posb[0]
    unsigned gg[4][4];
    {
        int4 idx = *(const int4*)(pebase);
        int id[4] = {idx.x, idx.y, idx.z, idx.w};
#pragma unroll
        for (int j = 0; j < 4; j++) {
            uint4 a = *(const uint4*)(peg + ((size_t)id[j] << 4));
            gg[0][j] = a.x; gg[1][j] = a.y; gg[2][j] = a.z; gg[3][j] = a.w;
        }
#pragma unroll
        for (int p = 0; p < 4; p++) {
            uint4 o = {gg[p][0], gg[p][1], gg[p][2], gg[p][3]};
            *(uint4*)&posb[0][p][gq][gk] = o;
        }
    }
    __syncthreads();

    for (int kt = 0; kt < 8; kt++) {
        int cur = kt & 1;
        // prefetch kt+1 gathers into regs (written to nxt buffer at end of compute)
        if (kt < 7) {
            int4 idx = *(const int4*)(pebase + (kt + 1) * 64);
            int id[4] = {idx.x, idx.y, idx.z, idx.w};
#pragma unroll
            for (int j = 0; j < 4; j++) {
                uint4 a = *(const uint4*)(peg + ((size_t)id[j] << 4));
                gg[0][j] = a.x; gg[1][j] = a.y; gg[2][j] = a.z; gg[3][j] = a.w;
            }
        }

        int ktg = kc * 8 + kt;
        // S^T = K x Q^T (32k x 32q), rows k=(r&3)+8*(r>>2)+4*hi, col q=q5
        f32x16 st[2];
#pragma unroll
        for (int ks = 0; ks < 2; ks++) {
            const unsigned short* kp = Kf + ((size_t)((bh * 16 + ktg) * 2 + ks) * 2) * 512 + lane * 8;
            short8 kf0 = *(const short8*)(kp);
            short8 kf1 = *(const short8*)(kp + 512);
            st[ks] = __builtin_amdgcn_mfma_f32_32x32x16_bf16(asbf(kf0), asbf(qf[0]), zero16, 0, 0, 0);
            st[ks] = __builtin_amdgcn_mfma_f32_32x32x16_bf16(asbf(kf1), asbf(qf[1]), st[ks], 0, 0, 0);
        }
        // pos add (b128 slab reads) + tile max
        float mx = -1e30f;
#pragma unroll
        for (int ks = 0; ks < 2; ks++)
#pragma unroll
            for (int rr = 0; rr < 4; rr++) {
                uint4 v = *(const uint4*)&posb[cur][slab][q5][ks * 32 + rr * 8 + hi * 4];
                unsigned pv[4] = {v.x, v.y, v.z, v.w};
#pragma unroll
                for (int c = 0; c < 4; c++) {
                    __half2 h2 = __builtin_bit_cast(__half2, pv[c]);
                    int r = rr * 4 + c;
                    st[ks][r] += halfsel ? __high2float(h2) : __low2float(h2);
                    mx = fmaxf(mx, st[ks][r]);
                }
            }
        mx = fmaxf(mx, __shfl_xor(mx, 32, 64));
        // defer-max (T13)
        if (!__all(mx <= m_run + 8.0f)) {
            float mn = fmaxf(m_run, mx);
            float fac = __expf(m_run - mn);
            m_run = mn;
            l_run *= fac;
#pragma unroll
            for (int r = 0; r < 16; r++) {
                int qrow = (r & 3) + 8 * (r >> 2) + 4 * hi;
                float facr = __shfl(fac, qrow, 64);
                accO[r] *= facr;
            }
        }
        float sum = 0.f;
#pragma unroll
        for (int ks = 0; ks < 2; ks++)
#pragma unroll
            for (int r = 0; r < 16; r++) {
                float p = __expf(st[ks][r] - m_run);
                st[ks][r] = p;
                sum += p;
            }
        sum += __shfl_xor(sum, 32, 64);
        l_run += sum;
        // P -> A-frag via v_cvt_pk_bf16_f32 + permlane32_swap (T12), then PV (coalesced V)
#pragma unroll
        for (int ks = 0; ks < 2; ks++) {
            unsigned pk_[8];
#pragma unroll
            for (int i = 0; i < 8; i++) {
                float plo = st[ks][2 * i], phi = st[ks][2 * i + 1];
                asm("v_cvt_pk_bf16_f32 %0, %1, %2" : "=v"(pk_[i]) : "v"(plo), "v"(phi));
            }
            asm("v_permlane32_swap_b32 %0, %1" : "+v"(pk_[0]), "+v"(pk_[2]));
            asm("v_permlane32_swap_b32 %0, %1" : "+v"(pk_[1]), "+v"(pk_[3]));
            asm("v_permlane32_swap_b32 %0, %1" : "+v"(pk_[4]), "+v"(pk_[6]));
            asm("v_permlane32_swap_b32 %0, %1" : "+v"(pk_[5]), "+v"(pk_[7]));
            uint4 u0 = {pk_[0], pk_[1], pk_[2], pk_[3]};
            uint4 u1 = {pk_[4], pk_[5], pk_[6], pk_[7]};
            short8 pa0 = __builtin_bit_cast(short8, u0);
            short8 pa1 = __builtin_bit_cast(short8, u1);
            const unsigned short* vp = Vf + ((size_t)((bh * 16 + ktg) * 2 + ks) * 2) * 512 + lane * 8;
            short8 vf0 = *(const short8*)(vp);
            short8 vf1 = *(const short8*)(vp + 512);
            accO = __builtin_amdgcn_mfma_f32_32x32x16_bf16(asbf(pa0), asbf(vf0), accO, 0, 0, 0);
            accO = __builtin_amdgcn_mfma_f32_32x32x16_bf16(asbf(pa1), asbf(vf1), accO, 0, 0, 0);
        }
        // write next tile's pos (nxt buffer; cur still being read by other waves — safe)
        if (kt < 7) {
#pragma unroll
            for (int p = 0; p < 4; p++) {
                uint4 o = {gg[p][0], gg[p][1], gg[p][2], gg[p][3]};
                *(uint4*)&posb[cur ^ 1][p][gq][gk] = o;
            }
        }
        __syncthreads();
    }

    // epilogue
    {
        size_t base = ((size_t)((b * 2 + kc) * 16 + head)) << 10;
#pragma unroll
        for (int r = 0; r < 16; r++) {
            int qrow = (r & 3) + 8 * (r >> 2) + 4 * hi;
            partial[(base + q0 + qrow) * 32 + q5] = accO[r];
        }
        if (hi == 0) {
            ml[(base + q0 + q5) * 2 + 0] = m_run;
            ml[(base + q0 + q5) * 2 + 1] = l_run;
            if (kc == 0)
                lbuf[(((size_t)((b << 4) + head)) << 10) + q0 + q5] = lb_;
        }
    }
}

// ---------------- combine partials + blank (x4 vectorized) ----------------
__global__ __launch_bounds__(256) void k_comb(const float* __restrict__ partial,
                                              const float* __restrict__ ml,
                                              const float* __restrict__ lbuf,
                                              const float* __restrict__ blank_v,
                                              unsigned short* __restrict__ attnO) {
    int t = blockIdx.x * 256 + threadIdx.x;     // 524288 threads
    int d4 = (t & 7) * 4;
    int row = t >> 3;                            // (b*16+h)*1024 + q
    int b = row >> 14, h = (row >> 10) & 15, q = row & 1023;
    size_t iA = ((size_t)((b * 2 + 0) * 16 + h) << 10) + q;
    size_t iB = ((size_t)((b * 2 + 1) * 16 + h) << 10) + q;
    float mA = ml[iA * 2], lA = ml[iA * 2 + 1];
    float mB = ml[iB * 2], lB = ml[iB * 2 + 1];
    float lb = lbuf[row];
    float M = fmaxf(mA, mB);
    float eA = __expf(mA - M), eB = __expf(mB - M);
    float L = lA * eA + lB * eB;
    float invL = 1.0f / L;
    float bw = __expf(lb - M) * invL;
    float4 pA = *(const float4*)&partial[iA * 32 + d4];
    float4 pB = *(const float4*)&partial[iB * 32 + d4];
    float4 bv = *(const float4*)&blank_v[h * 32 + d4];
    unsigned short o[4];
    o[0] = f2bf((pA.x * eA + pB.x * eB) * invL + bw * bv.x);
    o[1] = f2bf((pA.y * eA + pB.y * eB) * invL + bw * bv.y);
    o[2] = f2bf((pA.z * eA + pB.z * eB) * invL + bw * bv.z);
    o[3] = f2bf((pA.w * eA + pB.w * eB) * invL + bw * bv.w);
    *(uint2*)&attnO[((size_t)((b << 10) + q)) * 512 + h * 32 + d4] = *(uint2*)o;
}

// ---------------- final projection GEMM ----------------
__global__ __launch_bounds__(256) void k_proj(const unsigned short* __restrict__ A,
                                              const unsigned short* __restrict__ Bw,
                                              const float* __restrict__ bias,
                                              float* __restrict__ out) {
    __shared__ __align__(16) unsigned short As[128][72];
    __shared__ __align__(16) unsigned short Bs[64][72];
    int tid = threadIdx.x, lane = tid & 63, wid = tid >> 6;
    int m0 = blockIdx.y * 128, n0 = blockIdx.x * 64;
    int wm = wid >> 1, wn = wid & 1;
    f32x4 acc[4][2] = {};

    for (int k0 = 0; k0 < 512; k0 += 64) {
        {
            int row = tid >> 1, cs = (tid & 1) * 32;
            const short8* src = (const short8*)(A + (size_t)(m0 + row) * 512 + k0 + cs);
            short8* dst = (short8*)(&As[row][cs]);
            dst[0] = src[0]; dst[1] = src[1]; dst[2] = src[2]; dst[3] = src[3];
        }
        {
            int row = tid >> 2, cs = (tid & 3) * 16;
            const short8* src = (const short8*)(Bw + (size_t)(n0 + row) * 512 + k0 + cs);
            short8* dst = (short8*)(&Bs[row][cs]);
            dst[0] = src[0]; dst[1] = src[1];
        }
        __syncthreads();
#pragma unroll
        for (int kk = 0; kk < 64; kk += 32) {
            short8 a[4], b[2];
#pragma unroll
            for (int m = 0; m < 4; m++)
                a[m] = *(const short8*)(&As[wm * 64 + m * 16 + (lane & 15)][kk + ((lane >> 4) << 3)]);
#pragma unroll
            for (int n = 0; n < 2; n++)
                b[n] = *(const short8*)(&Bs[wn * 32 + n * 16 + (lane & 15)][kk + ((lane >> 4) << 3)]);
#pragma unroll
            for (int m = 0; m < 4; m++) {
#pragma unroll
                for (int n = 0; n < 2; n++)
                    acc[m][n] = __builtin_amdgcn_mfma_f32_16x16x32_bf16(asbf(a[m]), asbf(b[n]), acc[m][n], 0, 0, 0);
            }
        }
        __syncthreads();
    }
#pragma unroll
    for (int m = 0; m < 4; m++) {
#pragma unroll
        for (int n = 0; n < 2; n++) {
            int col = n0 + wn * 32 + n * 16 + (lane & 15);
            float bv = bias[col];
#pragma unroll
            for (int r = 0; r < 4; r++) {
                int row = m0 + wm * 64 + m * 16 + ((lane >> 4) << 2) + r;
                out[(size_t)row * 512 + col] = acc[m][n][r] + bv;
            }
        }
    }
}

extern "C" void kernel_launch(void* const* d_in, const int* in_sizes, int n_in,
                              void* d_out, int out_size, void* d_ws, size_t ws_size,
                              hipStream_t stream) {
    const float* feat    = (const float*)d_in[0];
    const int*   pe_idx  = (const int*)d_in[3];
    const float* pret    = (const float*)d_in[5];
    const float* qw      = (const float*)d_in[6];
    const float* qb      = (const float*)d_in[7];
    const float* kvw     = (const float*)d_in[8];
    const float* kvb     = (const float*)d_in[9];
    const float* pew     = (const float*)d_in[10];
    const float* peb     = (const float*)d_in[11];
    const float* blank_k = (const float*)d_in[12];
    const float* blank_v = (const float*)d_in[13];
    const float* projw   = (const float*)d_in[14];
    const float* projb   = (const float*)d_in[15];

    char* ws = (char*)d_ws;
    unsigned short* featb  = (unsigned short*)(ws);                  // 4 MB (reused as attnO)
    unsigned short* wqkv   = (unsigned short*)(ws + 4194304);        // 1.5 MB
    unsigned short* projwb = (unsigned short*)(ws + 5767168);        // 0.5 MB
    float*          bqkv   = (float*)(ws + 6291456);                 // 6 KB
    unsigned short* peAll  = (unsigned short*)(ws + 6297600);        // 128 KB
    unsigned short* Qf     = (unsigned short*)(ws + 6428672);        // 4 MB
    unsigned short* Kf     = (unsigned short*)(ws + 10622976);       // 4 MB
    unsigned short* Vf     = (unsigned short*)(ws + 14817280);       // 4 MB
    float*          partial= (float*)(ws + 19011584);                // 16 MB
    float*          mlb    = (float*)(ws + 35788800);                // 1 MB
    float*          lbuf   = (float*)(ws + 36837376);                // 256 KB
    unsigned short* attnO  = featb;                                  // alias (featb dead after k_qkv)

    k_prep<<<dim3(5382), dim3(256), 0, stream>>>(feat, qw, qb, kvw, kvb, pew, peb, pret, projw,
                                                 featb, wqkv, bqkv, projwb, peAll);
    k_qkv<<<dim3(24, 32), dim3(256), 0, stream>>>(featb, wqkv, bqkv, Qf, Kf, Vf);
    k_attn<<<dim3(512), dim3(512), 0, stream>>>(Qf, Kf, Vf, pe_idx, peAll, blank_k,
                                                partial, mlb, lbuf);
    k_comb<<<dim3(2048), dim3(256), 0, stream>>>(partial, mlb, lbuf, blank_v, attnO);
    k_proj<<<dim3(8, 32), dim3(256), 0, stream>>>(attnO, projwb, projb, (float*)d_out);
}